// Round 5
// baseline (249.822 us; speedup 1.0000x reference)
//
#include <hip/hip_runtime.h>
#include <math.h>

#define D 64
#define K 512
#define BLOCK 512
#define ROWS 256            // rows per block
#define CSTEP 256           // codes per staged e-tile
#define NSTEP (K / CSTEP)   // 2
#define NPART 32

// Bit-level emulation of the harness's numpy fp32 reference (validated at
// absmax 0.0):
//   dist[i,k] = fp32( fp32(sx[i] + se[k]) - 2*dot[i,k] )
// sx/se = numpy pairwise sums (8-accumulator kernel, contraction OFF),
// dot = sequential single-accumulator fmaf chain over j=0..63 (ascending).
// argmin strict-<, first occurrence (all merges lexicographic on (d,k)).
//
// Round-5: R2's 8x8/128x128 tile (best, 81.5us) was limited by LDS read
// density (16 ds_read_b128 per 256 wave-FMAs) + 6.7M conflict cycles +
// 2-wave/SIMD issue losses. This version: 8x16 thread tile, BLOCK=512,
// block = 256 rows x 256-code e-tiles -> 24 reads per 512 wave-FMAs (2x
// lower LDS demand), conflict-free swizzles (xa <=4-way, eb broadcast),
// sx/se from per-lane global reads (no LDS conflicts), 4 K-loop barriers,
// finalize fused into last-arriving block. 1 block/CU (147KB LDS) = 8
// waves = 2 waves/SIMD (same hiding regime as R2). Per-(row,k) arithmetic
// chains unchanged.

// numpy pairwise sum of v[j]*v[j], n=64; contraction OFF so each mul and
// add rounds separately, exactly like numpy's scalar kernel.
__device__ __forceinline__ float np_sumsq64(const float* v) {
#pragma clang fp contract(off)
    float r[8];
#pragma unroll
    for (int m = 0; m < 8; ++m) r[m] = v[m] * v[m];
#pragma unroll
    for (int i = 8; i < 64; i += 8) {
#pragma unroll
        for (int m = 0; m < 8; ++m) r[m] = r[m] + v[i + m] * v[i + m];
    }
    return ((r[0] + r[1]) + (r[2] + r[3])) + ((r[4] + r[5]) + (r[6] + r[7]));
}

__global__ __launch_bounds__(BLOCK, 1) void vq_fused(
    const float* __restrict__ x, const float* __restrict__ emb,
    float* __restrict__ q_out, float* __restrict__ idx_out,
    float* __restrict__ block_sums, int* __restrict__ part_hist,
    int* __restrict__ done_ctr,
    float* __restrict__ out_loss, float* __restrict__ out_perp,
    float inv_nelem, float inv_rows)
{
    // x tile: float4 idx = row*16 + (jc ^ ((row>>3)&7))      (64 KB)
    // e tile: float4 idx = cl*16  + (jc ^ ((cl>>4)&7))       (64 KB)
    __shared__ float4 xs4[ROWS * 16];
    __shared__ float4 es4[CSTEP * 16];
    __shared__ float sx_s[ROWS];            // 1 KB
    __shared__ float se_s[K];               // 2 KB
    __shared__ float2 bests[8 * ROWS];      // 16 KB: per-wave per-row (d,k)
    __shared__ float redf[BLOCK / 64];
    __shared__ double l8[BLOCK / 64], p8[BLOCK / 64];
    __shared__ int flag_s;

    const int tid = threadIdx.x;
    const int lane = tid & 63;
    const int wv = tid >> 6;
    const int rg = tid & 31;                // rows rg*8 .. rg*8+7
    const int cgrp = tid >> 5;              // 0..15: codes cgrp*16.. per step
    const int rowbase = blockIdx.x * ROWS;

    // ---- stage x tile (coalesced global -> swizzled LDS) ----
    const float4* xsrc = (const float4*)(x + (size_t)rowbase * D);
#pragma unroll
    for (int i = 0; i < (ROWS * 16) / BLOCK; ++i) {      // 8 float4/thread
        int f = tid + i * BLOCK;
        int row = f >> 4, jc = f & 15;
        xs4[row * 16 + (jc ^ ((row >> 3) & 7))] = xsrc[f];
    }

    // ---- se for all K codes (1/thread), per-lane GLOBAL reads ----
    {
        float er[D];
        const float4* e4 = (const float4*)(emb + (size_t)tid * D);
#pragma unroll
        for (int j = 0; j < 16; ++j) {
            float4 v = e4[j];
            er[4 * j + 0] = v.x; er[4 * j + 1] = v.y;
            er[4 * j + 2] = v.z; er[4 * j + 3] = v.w;
        }
        se_s[tid] = np_sumsq64(er);
    }

    // ---- sx for the block's rows (tid<256), per-lane GLOBAL reads ----
    if (tid < ROWS) {
        float xr[D];
        const float4* xp = (const float4*)(x + (size_t)(rowbase + tid) * D);
#pragma unroll
        for (int j = 0; j < 16; ++j) {
            float4 v = xp[j];
            xr[4 * j + 0] = v.x; xr[4 * j + 1] = v.y;
            xr[4 * j + 2] = v.z; xr[4 * j + 3] = v.w;
        }
        sx_s[tid] = np_sumsq64(xr);
    }

    float bd[8], bkf[8];
#pragma unroll
    for (int r = 0; r < 8; ++r) { bd[r] = INFINITY; bkf[r] = 0.f; }

    const int swx = rg & 7;                 // (row>>3)&7 for rows rg*8+r
    const int swe = cgrp & 7;               // (cl>>4)&7 for cl = cgrp*16+c
    const int xbyte = rg * 8 * 16;          // float4 base index of row rg*8

#pragma unroll 1
    for (int s = 0; s < NSTEP; ++s) {
        __syncthreads();    // prev step's es4 reads done / prologue done
        // ---- stage e tile ----
        const float4* esrc = (const float4*)(emb + (size_t)s * CSTEP * D);
#pragma unroll
        for (int i = 0; i < (CSTEP * 16) / BLOCK; ++i) {  // 8 float4/thread
            int f = tid + i * BLOCK;
            int cl = f >> 4, jc = f & 15;
            es4[cl * 16 + (jc ^ ((cl >> 4) & 7))] = esrc[f];
        }
        __syncthreads();

        float acc[8][16];
#pragma unroll
        for (int r = 0; r < 8; ++r)
#pragma unroll
            for (int c = 0; c < 16; ++c) acc[r][c] = 0.f;

        // 24 ds_read_b128 per 512 wave-FMAs; each acc is the sequential
        // ascending-j fmaf chain (x,y,z,w per jc).
#pragma unroll 2
        for (int jc = 0; jc < 16; ++jc) {
            float4 xa[8];
#pragma unroll
            for (int r = 0; r < 8; ++r)
                xa[r] = xs4[xbyte + r * 16 + (jc ^ swx)];
            // c-half A: codes c=0..7
            {
                float4 eb[8];
#pragma unroll
                for (int c = 0; c < 8; ++c)
                    eb[c] = es4[(cgrp * 16 + c) * 16 + (jc ^ swe)];
#pragma unroll
                for (int r = 0; r < 8; ++r)
#pragma unroll
                    for (int c = 0; c < 8; ++c) {
                        acc[r][c] = fmaf(xa[r].x, eb[c].x, acc[r][c]);
                        acc[r][c] = fmaf(xa[r].y, eb[c].y, acc[r][c]);
                        acc[r][c] = fmaf(xa[r].z, eb[c].z, acc[r][c]);
                        acc[r][c] = fmaf(xa[r].w, eb[c].w, acc[r][c]);
                    }
            }
            // c-half B: codes c=8..15
            {
                float4 eb[8];
#pragma unroll
                for (int c = 0; c < 8; ++c)
                    eb[c] = es4[(cgrp * 16 + 8 + c) * 16 + (jc ^ swe)];
#pragma unroll
                for (int r = 0; r < 8; ++r)
#pragma unroll
                    for (int c = 0; c < 8; ++c) {
                        acc[r][8 + c] = fmaf(xa[r].x, eb[c].x, acc[r][8 + c]);
                        acc[r][8 + c] = fmaf(xa[r].y, eb[c].y, acc[r][8 + c]);
                        acc[r][8 + c] = fmaf(xa[r].z, eb[c].z, acc[r][8 + c]);
                        acc[r][8 + c] = fmaf(xa[r].w, eb[c].w, acc[r][8 + c]);
                    }
            }
        }

        // dist + running first-min (steps ascending, c ascending, strict <)
        const int kglob = s * CSTEP + cgrp * 16;
        float sev[16];
#pragma unroll
        for (int c = 0; c < 16; ++c) sev[c] = se_s[kglob + c];
#pragma unroll
        for (int r = 0; r < 8; ++r) {
            const float sxv = sx_s[rg * 8 + r];
#pragma unroll
            for (int c = 0; c < 16; ++c) {
                float dcur = (sxv + sev[c]) - 2.0f * acc[r][c];  // ref rounding
                if (dcur < bd[r]) { bd[r] = dcur; bkf[r] = (float)(kglob + c); }
            }
        }
    }

    // ---- in-wave lexicographic merge across the 2 cgrps (lane^32) ----
#pragma unroll
    for (int r = 0; r < 8; ++r) {
        float od = __shfl_xor(bd[r], 32, 64);
        float ok = __shfl_xor(bkf[r], 32, 64);
        if (od < bd[r] || (od == bd[r] && ok < bkf[r])) { bd[r] = od; bkf[r] = ok; }
    }
    __syncthreads();        // es4 reads done (not reused, but orders bests)
    if (lane < 32) {
#pragma unroll
        for (int r = 0; r < 8; ++r)
            bests[wv * ROWS + lane * 8 + r] = make_float2(bd[r], bkf[r]);
    }
    __syncthreads();

    // ---- per-row final merge + gather/q/loss/idx (tid < 256) ----
    float s_loss = 0.f;
    if (tid < ROWS) {
        float bdd = INFINITY, bjf = 1e30f;
#pragma unroll
        for (int w = 0; w < 8; ++w) {
            float2 p = bests[w * ROWS + tid];
            if (p.x < bdd || (p.x == bdd && p.y < bjf)) { bdd = p.x; bjf = p.y; }
        }
        const int bi = (int)bjf;
        atomicAdd(&part_hist[(blockIdx.x & (NPART - 1)) * K + bi], 1);

        const int rowg = rowbase + tid;
        const float4* ep = (const float4*)(emb + (size_t)bi * D);
        float4* qp = (float4*)(q_out + (size_t)rowg * D);
        const int esw = (tid >> 3) & 7;
#pragma unroll
        for (int jc = 0; jc < 16; ++jc) {
            float4 xv = xs4[tid * 16 + (jc ^ esw)];   // bit-identical x copy
            float4 e  = ep[jc];
            float dx0 = e.x - xv.x, dx1 = e.y - xv.y;
            float dx2 = e.z - xv.z, dx3 = e.w - xv.w;
            s_loss = fmaf(dx0, dx0, s_loss);
            s_loss = fmaf(dx1, dx1, s_loss);
            s_loss = fmaf(dx2, dx2, s_loss);
            s_loss = fmaf(dx3, dx3, s_loss);
            float4 qs;  // straight-through: x + (q - x)
            qs.x = xv.x + dx0; qs.y = xv.y + dx1;
            qs.z = xv.z + dx2; qs.w = xv.w + dx3;
            qp[jc] = qs;
        }
        idx_out[rowg] = (float)bi;
    }

    // ---- loss partial (inactive waves contribute 0) ----
    for (int off = 32; off; off >>= 1) s_loss += __shfl_down(s_loss, off, 64);
    if (lane == 0) redf[wv] = s_loss;
    __syncthreads();
    if (tid == 0) {
        float tsum = 0.f;
#pragma unroll
        for (int w = 0; w < BLOCK / 64; ++w) tsum += redf[w];
        block_sums[blockIdx.x] = tsum;
    }

    // ---- completion ticket; last-arriving block finalizes ----
    __threadfence();
    __syncthreads();
    if (tid == 0) flag_s = atomicAdd(done_ctr, 1);
    __syncthreads();
    if (flag_s != (int)gridDim.x - 1) return;

    __threadfence();        // acquire side
    const int nblocks = (int)gridDim.x;
    double ls = 0.0;
    for (int i = tid; i < nblocks; i += BLOCK)
        ls += (double)__hip_atomic_load(&block_sums[i], __ATOMIC_RELAXED,
                                        __HIP_MEMORY_SCOPE_AGENT);
    double ps = 0.0;
    for (int k2 = tid; k2 < K; k2 += BLOCK) {
        int c = 0;
#pragma unroll
        for (int p = 0; p < NPART; ++p)
            c += __hip_atomic_load(&part_hist[p * K + k2], __ATOMIC_RELAXED,
                                   __HIP_MEMORY_SCOPE_AGENT);
        float pv = (float)c * inv_rows;
        ps += (double)(pv * logf(pv + 1e-10f));
    }
    for (int off = 32; off; off >>= 1) {
        ls += __shfl_down(ls, off, 64);
        ps += __shfl_down(ps, off, 64);
    }
    if (lane == 0) { l8[wv] = ls; p8[wv] = ps; }
    __syncthreads();
    if (tid == 0) {
        double L = 0.0, P = 0.0;
#pragma unroll
        for (int w = 0; w < BLOCK / 64; ++w) { L += l8[w]; P += p8[w]; }
        // loss = q_latent + 0.25*e_latent; forward values identical
        *out_loss = 1.25f * (float)(L * (double)inv_nelem);
        *out_perp = expf((float)(-P));
    }
}

extern "C" void kernel_launch(void* const* d_in, const int* in_sizes, int n_in,
                              void* d_out, int out_size, void* d_ws, size_t ws_size,
                              hipStream_t stream) {
    const float* x   = (const float*)d_in[0];
    const float* emb = (const float*)d_in[1];
    const int N = in_sizes[0] / D;          // 65536 rows
    const int nblocks = N / ROWS;           // 256

    float* out      = (float*)d_out;
    float* loss_out = out;                  // [0]
    float* q_out    = out + 1;              // [1 .. N*D]
    float* perp_out = out + 1 + (size_t)N * D;
    float* idx_out  = perp_out + 1;         // [.. + N]

    // ws: [block_sums: nblocks f32 | pad 256B][part_hist: 32*512 i32][ctr]
    float* block_sums = (float*)d_ws;
    int*   part_hist  = (int*)((char*)d_ws +
                               (((size_t)nblocks * 4 + 255) & ~(size_t)255));
    int*   done_ctr   = part_hist + (size_t)NPART * K;

    // one memset zeroes part_hist AND the ticket counter (contiguous)
    hipMemsetAsync(part_hist, 0, (size_t)NPART * K * sizeof(int) + sizeof(int),
                   stream);
    vq_fused<<<nblocks, BLOCK, 0, stream>>>(x, emb, q_out, idx_out,
                                            block_sums, part_hist, done_ctr,
                                            loss_out, perp_out,
                                            1.0f / (float)((size_t)N * D),
                                            1.0f / (float)N);
}